// Round 6
// baseline (182.974 us; speedup 1.0000x reference)
//
#include <hip/hip_runtime.h>
#include <hip/hip_bf16.h>

typedef unsigned short ushort_t;
typedef __attribute__((ext_vector_type(4))) float f32x4;
typedef __attribute__((ext_vector_type(8))) short bf16x8;
typedef __attribute__((ext_vector_type(8))) unsigned short u16x8;

#define M_DIM 2048
#define N_DIM 4096
#define K_DIM 4096
#define BM 256
#define BN 128
#define BK 64
#define NT (K_DIM / BK)   // 64 K-tiles

#define MFMA16(a, b, c) __builtin_amdgcn_mfma_f32_16x16x32_bf16((a), (b), (c), 0, 0, 0)

// ---------- helpers ----------
__device__ __forceinline__ unsigned short f2bf(float f) {
  unsigned int u = __float_as_uint(f);
  u += 0x7FFFu + ((u >> 16) & 1u);   // round-to-nearest-even
  return (unsigned short)(u >> 16);
}

__device__ __forceinline__ void async16(void* l, const void* g) {
  __builtin_amdgcn_global_load_lds(
      (const __attribute__((address_space(1))) void*)g,
      (__attribute__((address_space(3))) void*)l,
      16, 0, 0);
}

// ---------- kernel 1: fused [x fp32->bf16] + [W build, c1 staged in LDS] ----------
// (unchanged from round 5: ~26us)
__global__ void k_prep(const float* __restrict__ x, ushort_t* __restrict__ o,
                       const float* __restrict__ c0, const float* __restrict__ c1,
                       const float* __restrict__ c2, ushort_t* __restrict__ wt) {
  __shared__ float sc1[16 * 260];   // [i2][q*16+r], stride 260 (bank-spread)
  const int bid = blockIdx.x;
  const int tid = threadIdx.x;
  if (bid < 2048) {
    const int n4 = (M_DIM * K_DIM) / 4;
    for (int i = bid * 256 + tid; i < n4; i += 2048 * 256) {
      float4 v = ((const float4*)x)[i];
      ushort4 r;
      r.x = f2bf(v.x); r.y = f2bf(v.y); r.z = f2bf(v.z); r.w = f2bf(v.w);
      ((ushort4*)o)[i] = r;
    }
  } else {
    const int out = bid - 2048;               // 0..4095 = (o1,o2,o3)
    const int o3 = out & 15;
    const int o2 = (out >> 4) & 15;
    const int o1 = out >> 8;

    {
      const int q  = tid >> 4;
      const int i2 = tid & 15;
      const float* src = c1 + q * 4096 + i2 * 256 + o2 * 16;
      float* dst = &sc1[i2 * 260 + q * 16];
      #pragma unroll
      for (int rr = 0; rr < 4; ++rr)
        *(float4*)(dst + rr * 4) = *(const float4*)(src + rr * 4);
    }
    __syncthreads();

    const int i2 = tid & 15;
    const int i1 = tid >> 4;

    float4 a4[4];
    {
      const float* c0p = c0 + (i1 * 16 + o1) * 16;
      #pragma unroll
      for (int rr = 0; rr < 4; ++rr) a4[rr] = *(const float4*)(c0p + rr * 4);
    }

    float t01r[16];
    #pragma unroll
    for (int r = 0; r < 16; ++r) t01r[r] = 0.f;
    #pragma unroll
    for (int q = 0; q < 16; ++q) {
      const float a = a4[q >> 2][q & 3];
      const float* sp = &sc1[i2 * 260 + q * 16];
      #pragma unroll
      for (int rr = 0; rr < 4; ++rr) {
        float4 v = *(const float4*)(sp + rr * 4);
        t01r[rr * 4 + 0] += a * v.x;
        t01r[rr * 4 + 1] += a * v.y;
        t01r[rr * 4 + 2] += a * v.z;
        t01r[rr * 4 + 3] += a * v.w;
      }
    }

    u16x8 lo, hi;
    #pragma unroll
    for (int i3 = 0; i3 < 16; ++i3) {
      const float* c2p = c2 + i3 * 16 + o3;
      float s = 0.f;
      #pragma unroll
      for (int rr = 0; rr < 16; ++rr) s += t01r[rr] * c2p[rr * 256];
      ushort_t v = f2bf(s);
      if (i3 < 8) lo[i3] = v; else hi[i3 - 8] = v;
    }
    u16x8* dst = (u16x8*)(wt + ((size_t)out << 12) + (i1 << 8) + (i2 << 4));
    dst[0] = lo;
    dst[1] = hi;
  }
}

// ---------- kernel 2: GEMM C[M][N] = A[M][K] * Wt[N][K]^T + bias ----------
// A staged direct-to-registers (L2-served, pipelined 1 tile ahead, even/odd banks);
// B in swizzled triple-buffered LDS. ONE barrier + one counted vmcnt(8) per K-tile.
__global__ __launch_bounds__(512, 2) void k_gemm(
    const ushort_t* __restrict__ A,
    const ushort_t* __restrict__ Bt,
    const float* __restrict__ bias,
    float* __restrict__ C)
{
  __shared__ ushort_t lB[3][BN * BK];   // 3 x 16KB

  const int tid  = threadIdx.x;
  const int lane = tid & 63;
  const int wid  = tid >> 6;     // 0..7
  const int wm   = wid >> 1;     // 0..3  (M quadrant, 64 rows)
  const int wn   = wid & 1;      // 0..1  (N half, 64 cols)
  const int fr   = lane & 15;
  const int fg   = lane >> 4;    // 0..3

  // XCD swizzle: 256 wgs; bm = bid&7 -> each XCD owns one A-panel (2MB, L2-fit)
  const int bid = blockIdx.x;
  const int bm  = bid & 7;       // 0..7
  const int bn  = bid >> 3;      // 0..31

  // ---- B staging (linear LDS dest + inverse-swizzled global source) ----
  const int srow = tid >> 3;                               // 0..63
  const int scol = ((tid & 7) ^ (srow & 7)) << 3;          // swizzled source col (elems)
  const ushort_t* bSt = Bt + (size_t)(bn * BN + srow) * K_DIM + scol;
  const int dE = tid * 8;                                  // linear dest (elems)

#define STAGE_B(kt, s, r_) async16(&lB[s][(r_) * 4096 + dE], \
                                   bSt + (size_t)(kt) * BK + (size_t)(r_) * 64 * K_DIM)

  // ---- B fragment read addressing (swizzle applied on read; verified 0 conflicts) ----
  const int browb = wn * 64 + fr;                // + n*16
  const int cc0 = ( fg      ^ (fr & 7)) << 3;    // kk=0 col (elems)
  const int cc1 = ((fg + 4) ^ (fr & 7)) << 3;    // kk=1

  // ---- A fragment global addressing (direct to regs) ----
  // frag (m,kk) of tile kt: aBase + m*16*K + kt*64 + kk*32
  const ushort_t* aBase = A + (size_t)(bm * BM + wm * 64 + fr) * K_DIM + fg * 8;

#define LOADA(dst, kt) do {                                                          \
    _Pragma("unroll")                                                                \
    for (int m_ = 0; m_ < 4; ++m_) {                                                 \
      dst[m_][0] = *(const bf16x8*)(aBase + (size_t)m_ * 16 * K_DIM + (kt) * 64);    \
      dst[m_][1] = *(const bf16x8*)(aBase + (size_t)m_ * 16 * K_DIM + (kt) * 64 + 32);\
    }                                                                                \
  } while (0)

  f32x4 acc[4][4];
  #pragma unroll
  for (int m = 0; m < 4; ++m)
    #pragma unroll
    for (int n = 0; n < 4; ++n)
      acc[m][n] = (f32x4){0.f, 0.f, 0.f, 0.f};

  bf16x8 aE[4][2], aO[4][2];   // even/odd A register banks (static indexing)

  // prologue: stage B tiles 0,1; load A tile 0
  STAGE_B(0, 0, 0); STAGE_B(0, 0, 1);
  STAGE_B(1, 1, 0); STAGE_B(1, 1, 1);
  LOADA(aE, 0);
  // outstanding: B0(2) B1(2) A0(8) = 12 -> drain B0,B1; leave A0 in flight
  asm volatile("s_waitcnt vmcnt(8)" ::: "memory");
  __builtin_amdgcn_s_barrier();

  int sc = 0, ss = 2;

#define BODY(t, aCur, aNxt) do {                                                  \
    const bool pre_ = ((t) + 2 < NT);                                             \
    const ushort_t* pB_ = &lB[sc][0];                                             \
    if (pre_) { STAGE_B((t) + 2, ss, 0); STAGE_B((t) + 2, ss, 1); }               \
    bf16x8 bf0_[4], bf1_[4];                                                      \
    _Pragma("unroll")                                                             \
    for (int n_ = 0; n_ < 4; ++n_)                                                \
      bf0_[n_] = *(const bf16x8*)(pB_ + (browb + n_ * 16) * 64 + cc0);            \
    _Pragma("unroll")                                                             \
    for (int n_ = 0; n_ < 4; ++n_)                                                \
      bf1_[n_] = *(const bf16x8*)(pB_ + (browb + n_ * 16) * 64 + cc1);            \
    { const int ktn_ = ((t) + 1 < NT) ? (t) + 1 : (t);                            \
      LOADA(aNxt, ktn_); }                                                        \
    __builtin_amdgcn_s_setprio(1);                                                \
    _Pragma("unroll")                                                             \
    for (int m_ = 0; m_ < 4; ++m_)                                                \
      _Pragma("unroll")                                                           \
      for (int n_ = 0; n_ < 4; ++n_)                                              \
        acc[m_][n_] = MFMA16(aCur[m_][0], bf0_[n_], acc[m_][n_]);                 \
    _Pragma("unroll")                                                             \
    for (int m_ = 0; m_ < 4; ++m_)                                                \
      _Pragma("unroll")                                                           \
      for (int n_ = 0; n_ < 4; ++n_)                                              \
        acc[m_][n_] = MFMA16(aCur[m_][1], bf1_[n_], acc[m_][n_]);                 \
    __builtin_amdgcn_s_setprio(0);                                                \
    /* drain the 2 oldest (B stage for t+2 / last B tile); keep A(t+1) 8 loads */ \
    asm volatile("s_waitcnt vmcnt(8)" ::: "memory");                              \
    __builtin_amdgcn_s_barrier();                                                 \
    sc = (sc == 2) ? 0 : sc + 1;                                                  \
    ss = (ss == 2) ? 0 : ss + 1;                                                  \
  } while (0)

  for (int it = 0; it < NT / 2; ++it) {
    BODY(2 * it,     aE, aO);
    BODY(2 * it + 1, aO, aE);
  }
#undef BODY
#undef LOADA
#undef STAGE_B

  // epilogue: C/D layout col = lane&15, row = (lane>>4)*4 + reg
  const size_t row0 = (size_t)bm * BM + wm * 64;
  const int col0 = bn * BN + wn * 64;
  #pragma unroll
  for (int n = 0; n < 4; ++n) {
    const int col = col0 + n * 16 + fr;
    const float bv = bias[col];
    #pragma unroll
    for (int m = 0; m < 4; ++m) {
      const size_t r0 = row0 + m * 16 + fg * 4;
      #pragma unroll
      for (int r = 0; r < 4; ++r)
        C[(r0 + r) * N_DIM + col] = acc[m][n][r] + bv;
    }
  }
}

// ---------- launch ----------
extern "C" void kernel_launch(void* const* d_in, const int* in_sizes, int n_in,
                              void* d_out, int out_size, void* d_ws, size_t ws_size,
                              hipStream_t stream) {
  const float* x    = (const float*)d_in[0];
  const float* c0   = (const float*)d_in[1];
  const float* c1   = (const float*)d_in[2];
  const float* c2   = (const float*)d_in[3];
  const float* bias = (const float*)d_in[4];
  float* out = (float*)d_out;

  // workspace layout: Abf 16MB | Wt 32MB => 48MB needed
  const size_t NEED = (size_t)48 * 1024 * 1024;
  if (ws_size < NEED) return;

  char* ws = (char*)d_ws;
  ushort_t* Abf = (ushort_t*)ws;
  ushort_t* Wt  = (ushort_t*)(ws + (size_t)16 * 1024 * 1024);

  k_prep <<<6144, 256, 0, stream>>>(x, Abf, c0, c1, c2, Wt);
  k_gemm <<<256, 512, 0, stream>>>(Abf, Wt, bias, out);
}

// Round 7
// 109.219 us; speedup vs baseline: 1.6753x; 1.6753x over previous
//
#include <hip/hip_runtime.h>
#include <hip/hip_bf16.h>

typedef unsigned short ushort_t;
typedef __attribute__((ext_vector_type(4))) float f32x4;
typedef __attribute__((ext_vector_type(8))) short bf16x8;
typedef __attribute__((ext_vector_type(8))) unsigned short u16x8;

#define M_DIM 2048
#define N_DIM 4096
#define K_DIM 4096
#define BM 256
#define BN 128
#define BK 64
#define NT (K_DIM / BK)   // 64 K-tiles

#define MFMA16(a, b, c) __builtin_amdgcn_mfma_f32_16x16x32_bf16((a), (b), (c), 0, 0, 0)

// ---------- helpers ----------
__device__ __forceinline__ unsigned short f2bf(float f) {
  unsigned int u = __float_as_uint(f);
  u += 0x7FFFu + ((u >> 16) & 1u);   // round-to-nearest-even
  return (unsigned short)(u >> 16);
}

__device__ __forceinline__ void async16(void* l, const void* g) {
  __builtin_amdgcn_global_load_lds(
      (const __attribute__((address_space(1))) void*)g,
      (__attribute__((address_space(3))) void*)l,
      16, 0, 0);
}

// ---------- kernel 1: fused [x fp32->bf16] + [W build, c1 staged in LDS] ----------
// (unchanged from round 5: ~26us)
__global__ void k_prep(const float* __restrict__ x, ushort_t* __restrict__ o,
                       const float* __restrict__ c0, const float* __restrict__ c1,
                       const float* __restrict__ c2, ushort_t* __restrict__ wt) {
  __shared__ float sc1[16 * 260];   // [i2][q*16+r], stride 260 (bank-spread)
  const int bid = blockIdx.x;
  const int tid = threadIdx.x;
  if (bid < 2048) {
    const int n4 = (M_DIM * K_DIM) / 4;
    for (int i = bid * 256 + tid; i < n4; i += 2048 * 256) {
      float4 v = ((const float4*)x)[i];
      ushort4 r;
      r.x = f2bf(v.x); r.y = f2bf(v.y); r.z = f2bf(v.z); r.w = f2bf(v.w);
      ((ushort4*)o)[i] = r;
    }
  } else {
    const int out = bid - 2048;               // 0..4095 = (o1,o2,o3)
    const int o3 = out & 15;
    const int o2 = (out >> 4) & 15;
    const int o1 = out >> 8;

    {
      const int q  = tid >> 4;
      const int i2 = tid & 15;
      const float* src = c1 + q * 4096 + i2 * 256 + o2 * 16;
      float* dst = &sc1[i2 * 260 + q * 16];
      #pragma unroll
      for (int rr = 0; rr < 4; ++rr)
        *(float4*)(dst + rr * 4) = *(const float4*)(src + rr * 4);
    }
    __syncthreads();

    const int i2 = tid & 15;
    const int i1 = tid >> 4;

    float4 a4[4];
    {
      const float* c0p = c0 + (i1 * 16 + o1) * 16;
      #pragma unroll
      for (int rr = 0; rr < 4; ++rr) a4[rr] = *(const float4*)(c0p + rr * 4);
    }

    float t01r[16];
    #pragma unroll
    for (int r = 0; r < 16; ++r) t01r[r] = 0.f;
    #pragma unroll
    for (int q = 0; q < 16; ++q) {
      const float a = a4[q >> 2][q & 3];
      const float* sp = &sc1[i2 * 260 + q * 16];
      #pragma unroll
      for (int rr = 0; rr < 4; ++rr) {
        float4 v = *(const float4*)(sp + rr * 4);
        t01r[rr * 4 + 0] += a * v.x;
        t01r[rr * 4 + 1] += a * v.y;
        t01r[rr * 4 + 2] += a * v.z;
        t01r[rr * 4 + 3] += a * v.w;
      }
    }

    u16x8 lo, hi;
    #pragma unroll
    for (int i3 = 0; i3 < 16; ++i3) {
      const float* c2p = c2 + i3 * 16 + o3;
      float s = 0.f;
      #pragma unroll
      for (int rr = 0; rr < 16; ++rr) s += t01r[rr] * c2p[rr * 256];
      ushort_t v = f2bf(s);
      if (i3 < 8) lo[i3] = v; else hi[i3 - 8] = v;
    }
    u16x8* dst = (u16x8*)(wt + ((size_t)out << 12) + (i1 << 8) + (i2 << 4));
    dst[0] = lo;
    dst[1] = hi;
  }
}

// ---------- kernel 2: GEMM C[M][N] = A[M][K] * Wt[N][K]^T + bias ----------
// Round-5 base (A+B in swizzled triple-buffered LDS, counted vmcnt(6)/tile) +
// register-pipelined fragments: ds_reads always fetch the NEXT half-tile while
// MFMA consumes the current one -> LDS pipe streams under the matrix pipe.
__global__ __launch_bounds__(512, 2) void k_gemm(
    const ushort_t* __restrict__ A,
    const ushort_t* __restrict__ Bt,
    const float* __restrict__ bias,
    float* __restrict__ C)
{
  __shared__ ushort_t lA[3][BM * BK];   // 3 x 32KB
  __shared__ ushort_t lB[3][BN * BK];   // 3 x 16KB  (total 144KB)

  const int tid  = threadIdx.x;
  const int lane = tid & 63;
  const int wid  = tid >> 6;     // 0..7
  const int wm   = wid >> 1;     // 0..3  (M quadrant, 64 rows)
  const int wn   = wid & 1;      // 0..1  (N half, 64 cols)
  const int fr   = lane & 15;
  const int fg   = lane >> 4;    // 0..3

  // XCD swizzle: 256 wgs; bm = bid&7 -> each XCD owns one A-panel (2MB, L2-fit)
  const int bid = blockIdx.x;
  const int bm  = bid & 7;       // 0..7
  const int bn  = bid >> 3;      // 0..31

  // ---- staging (linear LDS dest + inverse-swizzled global source) ----
  const int srow = tid >> 3;                               // 0..63
  const int scol = ((tid & 7) ^ (srow & 7)) << 3;          // swizzled source col (elems)
  const ushort_t* aSt = A  + (size_t)(bm * BM + srow) * K_DIM + scol;
  const ushort_t* bSt = Bt + (size_t)(bn * BN + srow) * K_DIM + scol;
  const int dE = tid * 8;                                  // linear dest (elems)

#define STAGE_A(kt, s, r_) async16(&lA[s][(r_) * 4096 + dE], \
                                   aSt + (size_t)(kt) * BK + (size_t)(r_) * 64 * K_DIM)
#define STAGE_B(kt, s, r_) async16(&lB[s][(r_) * 4096 + dE], \
                                   bSt + (size_t)(kt) * BK + (size_t)(r_) * 64 * K_DIM)

  // ---- fragment read addressing (swizzle applied on read; verified 0 conflicts) ----
  const int arowb = wm * 64 + fr;                // + m*16
  const int browb = wn * 64 + fr;                // + n*16
  const int cc0 = ( fg      ^ (fr & 7)) << 3;    // kk=0 col (elems)
  const int cc1 = ((fg + 4) ^ (fr & 7)) << 3;    // kk=1

  f32x4 acc[4][4];
  #pragma unroll
  for (int m = 0; m < 4; ++m)
    #pragma unroll
    for (int n = 0; n < 4; ++n)
      acc[m][n] = (f32x4){0.f, 0.f, 0.f, 0.f};

  // prologue: stage tiles 0,1 (6 chunks each)
  #pragma unroll
  for (int r_ = 0; r_ < 4; ++r_) STAGE_A(0, 0, r_);
  #pragma unroll
  for (int r_ = 0; r_ < 2; ++r_) STAGE_B(0, 0, r_);
  #pragma unroll
  for (int r_ = 0; r_ < 4; ++r_) STAGE_A(1, 1, r_);
  #pragma unroll
  for (int r_ = 0; r_ < 2; ++r_) STAGE_B(1, 1, r_);

  asm volatile("s_waitcnt vmcnt(6)" ::: "memory");   // tile 0 resident (per-wave)
  __builtin_amdgcn_s_barrier();                      // ... for ALL waves

  // preload tile-0 half-0 fragments
  bf16x8 curA[4], curB[4], nxtA[4], nxtB[4];
  #pragma unroll
  for (int m = 0; m < 4; ++m) curA[m] = *(const bf16x8*)(&lA[0][0] + (arowb + m * 16) * 64 + cc0);
  #pragma unroll
  for (int n = 0; n < 4; ++n) curB[n] = *(const bf16x8*)(&lB[0][0] + (browb + n * 16) * 64 + cc0);

  int sc = 0, ss = 2;
  for (int t = 0; t < NT; ++t) {
    const bool pre = (t + 2 < NT);
    const ushort_t* pA = &lA[sc][0];
    const ushort_t* pB = &lB[sc][0];

    // ---- read half-1 fragments of tile t (consumed at end of this body) ----
    #pragma unroll
    for (int m = 0; m < 4; ++m) nxtA[m] = *(const bf16x8*)(pA + (arowb + m * 16) * 64 + cc1);
    #pragma unroll
    for (int n = 0; n < 4; ++n) nxtB[n] = *(const bf16x8*)(pB + (browb + n * 16) * 64 + cc1);

    // ---- stage A-chunks of tile t+2 ----
    if (pre) { STAGE_A(t + 2, ss, 0); STAGE_A(t + 2, ss, 1);
               STAGE_A(t + 2, ss, 2); STAGE_A(t + 2, ss, 3); }

    // ---- MFMA half-0 (fragments loaded one half ahead) ----
    __builtin_amdgcn_s_setprio(1);
    #pragma unroll
    for (int m = 0; m < 4; ++m)
      #pragma unroll
      for (int n = 0; n < 4; ++n)
        acc[m][n] = MFMA16(curA[m], curB[n], acc[m][n]);
    __builtin_amdgcn_s_setprio(0);

    // ---- read half-0 fragments of tile t+1 (slot sc+1; staged data resident
    //      since end of tile t-1 by the vmcnt(6) invariant) ----
    if (t + 1 < NT) {
      if (t == NT - 2) {   // only tile whose next-tile stage may still be in flight
        asm volatile("s_waitcnt vmcnt(0)" ::: "memory");
        __builtin_amdgcn_s_barrier();
      }
      const int sn = (sc == 2) ? 0 : sc + 1;
      const ushort_t* qA = &lA[sn][0];
      const ushort_t* qB = &lB[sn][0];
      #pragma unroll
      for (int m = 0; m < 4; ++m) curA[m] = *(const bf16x8*)(qA + (arowb + m * 16) * 64 + cc0);
      #pragma unroll
      for (int n = 0; n < 4; ++n) curB[n] = *(const bf16x8*)(qB + (browb + n * 16) * 64 + cc0);
    }

    // ---- stage B-chunks of tile t+2 ----
    if (pre) { STAGE_B(t + 2, ss, 0); STAGE_B(t + 2, ss, 1); }

    // ---- MFMA half-1 ----
    __builtin_amdgcn_s_setprio(1);
    #pragma unroll
    for (int m = 0; m < 4; ++m)
      #pragma unroll
      for (int n = 0; n < 4; ++n)
        acc[m][n] = MFMA16(nxtA[m], nxtB[n], acc[m][n]);
    __builtin_amdgcn_s_setprio(0);

    // ---- tile end: drain stage(t+1) fully (6 newest = stage(t+2) stay in flight) ----
    if (t + 2 < NT)      asm volatile("s_waitcnt vmcnt(6)" ::: "memory");
    else                 asm volatile("s_waitcnt vmcnt(0)" ::: "memory");
    __builtin_amdgcn_s_barrier();

    sc = (sc == 2) ? 0 : sc + 1;
    ss = (ss == 2) ? 0 : ss + 1;
  }
#undef STAGE_A
#undef STAGE_B

  // epilogue: C/D layout col = lane&15, row = (lane>>4)*4 + reg
  const size_t row0 = (size_t)bm * BM + wm * 64;
  const int col0 = bn * BN + wn * 64;
  #pragma unroll
  for (int n = 0; n < 4; ++n) {
    const int col = col0 + n * 16 + fr;
    const float bv = bias[col];
    #pragma unroll
    for (int m = 0; m < 4; ++m) {
      const size_t r0 = row0 + m * 16 + fg * 4;
      #pragma unroll
      for (int r = 0; r < 4; ++r)
        C[(r0 + r) * N_DIM + col] = acc[m][n][r] + bv;
    }
  }
}

// ---------- launch ----------
extern "C" void kernel_launch(void* const* d_in, const int* in_sizes, int n_in,
                              void* d_out, int out_size, void* d_ws, size_t ws_size,
                              hipStream_t stream) {
  const float* x    = (const float*)d_in[0];
  const float* c0   = (const float*)d_in[1];
  const float* c1   = (const float*)d_in[2];
  const float* c2   = (const float*)d_in[3];
  const float* bias = (const float*)d_in[4];
  float* out = (float*)d_out;

  // workspace layout: Abf 16MB | Wt 32MB => 48MB needed
  const size_t NEED = (size_t)48 * 1024 * 1024;
  if (ws_size < NEED) return;

  char* ws = (char*)d_ws;
  ushort_t* Abf = (ushort_t*)ws;
  ushort_t* Wt  = (ushort_t*)(ws + (size_t)16 * 1024 * 1024);

  k_prep <<<6144, 256, 0, stream>>>(x, Abf, c0, c1, c2, Wt);
  k_gemm <<<256, 512, 0, stream>>>(Abf, Wt, bias, out);
}

// Round 8
// 108.274 us; speedup vs baseline: 1.6899x; 1.0087x over previous
//
#include <hip/hip_runtime.h>
#include <hip/hip_bf16.h>

typedef unsigned short ushort_t;
typedef __attribute__((ext_vector_type(4))) float f32x4;
typedef __attribute__((ext_vector_type(8))) short bf16x8;
typedef __attribute__((ext_vector_type(8))) unsigned short u16x8;

#define M_DIM 2048
#define N_DIM 4096
#define K_DIM 4096
#define BM 128
#define BN 256
#define BK 64
#define NT (K_DIM / BK)   // 64 K-tiles

#define MFMA16(a, b, c) __builtin_amdgcn_mfma_f32_16x16x32_bf16((a), (b), (c), 0, 0, 0)

// ---------- helpers ----------
__device__ __forceinline__ unsigned short f2bf(float f) {
  unsigned int u = __float_as_uint(f);
  u += 0x7FFFu + ((u >> 16) & 1u);   // round-to-nearest-even
  return (unsigned short)(u >> 16);
}

__device__ __forceinline__ void async16(void* l, const void* g) {
  __builtin_amdgcn_global_load_lds(
      (const __attribute__((address_space(1))) void*)g,
      (__attribute__((address_space(3))) void*)l,
      16, 0, 0);
}

// ---------- kernel 1: fused [x fp32->bf16] + [W build, c1 staged in LDS] ----------
// (unchanged from round 5: ~26us)
__global__ void k_prep(const float* __restrict__ x, ushort_t* __restrict__ o,
                       const float* __restrict__ c0, const float* __restrict__ c1,
                       const float* __restrict__ c2, ushort_t* __restrict__ wt) {
  __shared__ float sc1[16 * 260];   // [i2][q*16+r], stride 260 (bank-spread)
  const int bid = blockIdx.x;
  const int tid = threadIdx.x;
  if (bid < 2048) {
    const int n4 = (M_DIM * K_DIM) / 4;
    for (int i = bid * 256 + tid; i < n4; i += 2048 * 256) {
      float4 v = ((const float4*)x)[i];
      ushort4 r;
      r.x = f2bf(v.x); r.y = f2bf(v.y); r.z = f2bf(v.z); r.w = f2bf(v.w);
      ((ushort4*)o)[i] = r;
    }
  } else {
    const int out = bid - 2048;               // 0..4095 = (o1,o2,o3)
    const int o3 = out & 15;
    const int o2 = (out >> 4) & 15;
    const int o1 = out >> 8;

    {
      const int q  = tid >> 4;
      const int i2 = tid & 15;
      const float* src = c1 + q * 4096 + i2 * 256 + o2 * 16;
      float* dst = &sc1[i2 * 260 + q * 16];
      #pragma unroll
      for (int rr = 0; rr < 4; ++rr)
        *(float4*)(dst + rr * 4) = *(const float4*)(src + rr * 4);
    }
    __syncthreads();

    const int i2 = tid & 15;
    const int i1 = tid >> 4;

    float4 a4[4];
    {
      const float* c0p = c0 + (i1 * 16 + o1) * 16;
      #pragma unroll
      for (int rr = 0; rr < 4; ++rr) a4[rr] = *(const float4*)(c0p + rr * 4);
    }

    float t01r[16];
    #pragma unroll
    for (int r = 0; r < 16; ++r) t01r[r] = 0.f;
    #pragma unroll
    for (int q = 0; q < 16; ++q) {
      const float a = a4[q >> 2][q & 3];
      const float* sp = &sc1[i2 * 260 + q * 16];
      #pragma unroll
      for (int rr = 0; rr < 4; ++rr) {
        float4 v = *(const float4*)(sp + rr * 4);
        t01r[rr * 4 + 0] += a * v.x;
        t01r[rr * 4 + 1] += a * v.y;
        t01r[rr * 4 + 2] += a * v.z;
        t01r[rr * 4 + 3] += a * v.w;
      }
    }

    u16x8 lo, hi;
    #pragma unroll
    for (int i3 = 0; i3 < 16; ++i3) {
      const float* c2p = c2 + i3 * 16 + o3;
      float s = 0.f;
      #pragma unroll
      for (int rr = 0; rr < 16; ++rr) s += t01r[rr] * c2p[rr * 256];
      ushort_t v = f2bf(s);
      if (i3 < 8) lo[i3] = v; else hi[i3 - 8] = v;
    }
    u16x8* dst = (u16x8*)(wt + ((size_t)out << 12) + (i1 << 8) + (i2 << 4));
    dst[0] = lo;
    dst[1] = hi;
  }
}

// ---------- kernel 2: GEMM C[M][N] = A[M][K] * Wt[N][K]^T + bias ----------
// 4 waves (256 thr), wave tile 128x64 (1M x 4N over BM=128 BN=256): per-CU LDS
// reads drop 128KB -> 96KB/tile (compute-dominant). Triple-buffered swizzled
// LDS, one counted vmcnt(12) + one barrier per K-tile (provably race-free).
__global__ __launch_bounds__(256, 1) void k_gemm(
    const ushort_t* __restrict__ A,
    const ushort_t* __restrict__ Bt,
    const float* __restrict__ bias,
    float* __restrict__ C)
{
  __shared__ ushort_t lA[3][BM * BK];   // 3 x 16KB
  __shared__ ushort_t lB[3][BN * BK];   // 3 x 32KB  (total 144KB)

  const int tid  = threadIdx.x;
  const int lane = tid & 63;
  const int wid  = tid >> 6;     // 0..3 (N quadrant, 64 cols each)
  const int fr   = lane & 15;
  const int fg   = lane >> 4;    // 0..3

  // 2-level XCD swizzle: xcd=bid&7 owns an 8bm x 4bn region (A 8MB + B 8MB L2-fit)
  const int bid = blockIdx.x;
  const int xcd = bid & 7;
  const int l   = bid >> 3;                  // 0..31
  const int bm  = (xcd & 1) * 8 + (l & 7);   // 0..15
  const int bn  = (xcd >> 1) * 4 + (l >> 3); // 0..15

  // ---- staging (linear LDS dest + inverse-swizzled global source) ----
  const int srow = tid >> 3;                               // 0..31
  const int scol = ((tid & 7) ^ (srow & 7)) << 3;          // swizzled source col (elems)
  const ushort_t* aSt = A  + (size_t)(bm * BM + srow) * K_DIM + scol;
  const ushort_t* bSt = Bt + (size_t)(bn * BN + srow) * K_DIM + scol;
  const int dE = tid * 8;                                  // linear dest (elems)

  // chunk r_: 32 rows; A has 4 chunks, B has 8
#define STAGE_A(kt, s, r_) async16(&lA[s][(r_) * 2048 + dE], \
                                   aSt + (size_t)(kt) * BK + (size_t)(r_) * 32 * K_DIM)
#define STAGE_B(kt, s, r_) async16(&lB[s][(r_) * 2048 + dE], \
                                   bSt + (size_t)(kt) * BK + (size_t)(r_) * 32 * K_DIM)

  // ---- fragment read addressing (swizzle applied on read; verified 0 conflicts) ----
  // A: all waves read rows m*16+fr (m=0..7); B: wave reads cols wid*64 + n*16+fr
  const int browb = wid * 64 + fr;
  const int cc0 = ( fg      ^ (fr & 7)) << 3;    // kk=0 col (elems)
  const int cc1 = ((fg + 4) ^ (fr & 7)) << 3;    // kk=1

  f32x4 acc[8][4];
  #pragma unroll
  for (int m = 0; m < 8; ++m)
    #pragma unroll
    for (int n = 0; n < 4; ++n)
      acc[m][n] = (f32x4){0.f, 0.f, 0.f, 0.f};

  // prologue: stage tiles 0,1 (12 chunks each)
  #pragma unroll
  for (int r_ = 0; r_ < 4; ++r_) STAGE_A(0, 0, r_);
  #pragma unroll
  for (int r_ = 0; r_ < 8; ++r_) STAGE_B(0, 0, r_);
  #pragma unroll
  for (int r_ = 0; r_ < 4; ++r_) STAGE_A(1, 1, r_);
  #pragma unroll
  for (int r_ = 0; r_ < 8; ++r_) STAGE_B(1, 1, r_);

  asm volatile("s_waitcnt vmcnt(12)" ::: "memory");  // tile 0 resident
  __builtin_amdgcn_s_barrier();

  int sc = 0, ss = 2;
  for (int t = 0; t < NT; ++t) {
    const bool pre = (t + 2 < NT);
    const ushort_t* pA = &lA[sc][0];
    const ushort_t* pB = &lB[sc][0];

    // ---- half 0 (kk=0): read frags, stage A + B[0..1], 32 MFMA ----
    {
      bf16x8 af[8], bf[4];
      #pragma unroll
      for (int m = 0; m < 8; ++m) af[m] = *(const bf16x8*)(pA + (m * 16 + fr) * 64 + cc0);
      #pragma unroll
      for (int n = 0; n < 4; ++n) bf[n] = *(const bf16x8*)(pB + (browb + n * 16) * 64 + cc0);
      if (pre) {
        STAGE_A(t + 2, ss, 0); STAGE_A(t + 2, ss, 1);
        STAGE_A(t + 2, ss, 2); STAGE_A(t + 2, ss, 3);
        STAGE_B(t + 2, ss, 0); STAGE_B(t + 2, ss, 1);
      }
      __builtin_amdgcn_s_setprio(1);
      #pragma unroll
      for (int m = 0; m < 8; ++m)
        #pragma unroll
        for (int n = 0; n < 4; ++n)
          acc[m][n] = MFMA16(af[m], bf[n], acc[m][n]);
      __builtin_amdgcn_s_setprio(0);
    }

    // ---- half 1 (kk=1): read frags, stage B[2..7], 32 MFMA ----
    {
      bf16x8 af[8], bf[4];
      #pragma unroll
      for (int m = 0; m < 8; ++m) af[m] = *(const bf16x8*)(pA + (m * 16 + fr) * 64 + cc1);
      #pragma unroll
      for (int n = 0; n < 4; ++n) bf[n] = *(const bf16x8*)(pB + (browb + n * 16) * 64 + cc1);
      if (pre) {
        STAGE_B(t + 2, ss, 2); STAGE_B(t + 2, ss, 3);
        STAGE_B(t + 2, ss, 4); STAGE_B(t + 2, ss, 5);
        STAGE_B(t + 2, ss, 6); STAGE_B(t + 2, ss, 7);
      }
      __builtin_amdgcn_s_setprio(1);
      #pragma unroll
      for (int m = 0; m < 8; ++m)
        #pragma unroll
        for (int n = 0; n < 4; ++n)
          acc[m][n] = MFMA16(af[m], bf[n], acc[m][n]);
      __builtin_amdgcn_s_setprio(0);
    }

    // ---- tile end: drain stage(t+1) (leave newest 12 = stage(t+2)) ----
    if (pre) asm volatile("s_waitcnt vmcnt(12)" ::: "memory");
    else     asm volatile("s_waitcnt vmcnt(0)"  ::: "memory");
    __builtin_amdgcn_s_barrier();

    sc = (sc == 2) ? 0 : sc + 1;
    ss = (ss == 2) ? 0 : ss + 1;
  }
#undef STAGE_A
#undef STAGE_B

  // epilogue: C/D layout col = lane&15, row = (lane>>4)*4 + reg
  const size_t row0 = (size_t)bm * BM;
  const int col0 = bn * BN + wid * 64;
  #pragma unroll
  for (int n = 0; n < 4; ++n) {
    const int col = col0 + n * 16 + fr;
    const float bv = bias[col];
    #pragma unroll
    for (int m = 0; m < 8; ++m) {
      const size_t r0 = row0 + m * 16 + fg * 4;
      #pragma unroll
      for (int r = 0; r < 4; ++r)
        C[(r0 + r) * N_DIM + col] = acc[m][n][r] + bv;
    }
  }
}

// ---------- launch ----------
extern "C" void kernel_launch(void* const* d_in, const int* in_sizes, int n_in,
                              void* d_out, int out_size, void* d_ws, size_t ws_size,
                              hipStream_t stream) {
  const float* x    = (const float*)d_in[0];
  const float* c0   = (const float*)d_in[1];
  const float* c1   = (const float*)d_in[2];
  const float* c2   = (const float*)d_in[3];
  const float* bias = (const float*)d_in[4];
  float* out = (float*)d_out;

  // workspace layout: Abf 16MB | Wt 32MB => 48MB needed
  const size_t NEED = (size_t)48 * 1024 * 1024;
  if (ws_size < NEED) return;

  char* ws = (char*)d_ws;
  ushort_t* Abf = (ushort_t*)ws;
  ushort_t* Wt  = (ushort_t*)(ws + (size_t)16 * 1024 * 1024);

  k_prep <<<6144, 256, 0, stream>>>(x, Abf, c0, c1, c2, Wt);
  k_gemm <<<256, 256, 0, stream>>>(Abf, Wt, bias, out);
}